// Round 6
// baseline (203.977 us; speedup 1.0000x reference)
//
#include <hip/hip_runtime.h>

#define B_DIM 1024
#define C_DIM 256
#define ELL   9
#define E_DIM 10
#define K1    1
#define K2    4
#define K3    20

#define N_CUBIC 165                 // monomials a<=b<=c
#define N_QUAD  45                  // pairs a<=b
// q-sliced table layout: per q: [165*20 cubic][45*4 quad][9 lin][3 pad]
#define Q_CUBIC 0
#define Q_QUAD  (N_CUBIC * K3)              // 3300
#define Q_LIN   (Q_QUAD + N_QUAD * K2)      // 3480
#define Q_SIZE  3492                        // padded to 16B multiple
#define TBL_FLOATS (4 * Q_SIZE)             // 13968
#define MONO3_OFF  TBL_FLOATS               // int region after floats
#define MONO2_OFF  (MONO3_OFF + N_CUBIC)
#define WS_TOTAL   (MONO2_OFF + N_QUAD)     // 14178 words

// ---------------------------------------------------------------------------
// Kernel A: build q-sliced symmetrized tables + packed monomial decode words.
// mono3[m] = pair_index(a,b) | (c2 << 8); mono2[p] = a | (b<<4).
// ---------------------------------------------------------------------------
__global__ void build_tables(const float* __restrict__ U1_l0,
                             const float* __restrict__ U2_l0,
                             const float* __restrict__ U3_l0,
                             const float* __restrict__ U1_l1,
                             const float* __restrict__ U2_l1,
                             const float* __restrict__ U3_l1,
                             float* __restrict__ tbl)
{
    int idx = blockIdx.x * blockDim.x + threadIdx.x;
    if (idx >= WS_TOTAL) return;

    if (idx < TBL_FLOATS) {
        int q = idx / Q_SIZE;       // 0 = l0; 1..3 = l1 v=q-1
        int r = idx % Q_SIZE;
        int v = q - 1;
        float s = 0.f;
        if (r < Q_QUAD) {
            int m = r / K3, k = r % K3;
            int a = 0, b = 0, c = 0, cnt = 0;
            for (int ai = 0; ai < ELL; ++ai)
                for (int bi = ai; bi < ELL; ++bi)
                    for (int ci = bi; ci < ELL; ++ci) {
                        if (cnt == m) { a = ai; b = bi; c = ci; }
                        ++cnt;
                    }
            int P[6][3] = {{a,b,c},{a,c,b},{b,a,c},{b,c,a},{c,a,b},{c,b,a}};
            for (int t = 0; t < 6; ++t) {
                bool dup = false;
                for (int u = 0; u < t; ++u)
                    if (P[u][0]==P[t][0] && P[u][1]==P[t][1] && P[u][2]==P[t][2]) { dup = true; break; }
                if (dup) continue;
                int p0 = P[t][0], p1 = P[t][1], p2 = P[t][2];
                if (q == 0) s += U3_l0[((p0*ELL + p1)*ELL + p2)*K3 + k];
                else        s += U3_l1[(((v*ELL + p0)*ELL + p1)*ELL + p2)*K3 + k];
            }
        } else if (r < Q_LIN) {
            int rr = r - Q_QUAD;
            int p = rr / K2, k = rr % K2;
            int a = 0, b = 0, cnt = 0;
            for (int ai = 0; ai < ELL; ++ai)
                for (int bi = ai; bi < ELL; ++bi) {
                    if (cnt == p) { a = ai; b = bi; }
                    ++cnt;
                }
            for (int t = 0; t < 2; ++t) {
                if (t == 1 && a == b) break;
                int p0 = (t == 0) ? a : b;
                int p1 = (t == 0) ? b : a;
                if (q == 0) s += U2_l0[(p0*ELL + p1)*K2 + k];
                else        s += U2_l1[((v*ELL + p0)*ELL + p1)*K2 + k];
            }
        } else if (r < Q_LIN + ELL) {
            int i = r - Q_LIN;
            s = (q == 0) ? U1_l0[i] : U1_l1[v*ELL + i];
        } else {
            s = 0.f;   // pad
        }
        tbl[idx] = s;
    } else if (idx < MONO2_OFF) {
        int m = idx - MONO3_OFF;
        int a = 0, b = 0, c = 0, cnt = 0;
        for (int ai = 0; ai < ELL; ++ai)
            for (int bi = ai; bi < ELL; ++bi)
                for (int ci = bi; ci < ELL; ++ci) {
                    if (cnt == m) { a = ai; b = bi; c = ci; }
                    ++cnt;
                }
        // pair index of (a,b) in lex order over a<=b
        int p = 0, pc = 0;
        for (int ai = 0; ai < ELL; ++ai)
            for (int bi = ai; bi < ELL; ++bi) {
                if (ai == a && bi == b) p = pc;
                ++pc;
            }
        ((int*)tbl)[idx] = p | (c << 8);
    } else {
        int p = idx - MONO2_OFF;
        int a = 0, b = 0, cnt = 0;
        for (int ai = 0; ai < ELL; ++ai)
            for (int bi = ai; bi < ELL; ++bi) {
                if (cnt == p) { a = ai; b = bi; }
                ++cnt;
            }
        ((int*)tbl)[idx] = a | (b << 4);
    }
}

// ---------------------------------------------------------------------------
// Kernel B v6: 256 threads per block, one block per b. Wave w = output group
// q (readfirstlane -> SGPR). Each thread owns 4 CONTIGUOUS c's: every table
// float (s_load, SGPR operand) feeds 4 FMAs -> operand delivery amortized 4x.
// Pair products P2[45][256] staged once per block in LDS; cubic iteration is
// 2x ds_read_b128 (lane-contiguous, conflict-free) + 4 mul + 80 FMA.
// All accumulator indices compile-time (rule #20).
// ---------------------------------------------------------------------------
__global__ __launch_bounds__(256, 2) void symcon_main(
    const float* __restrict__ x,  const float* __restrict__ y,
    const float* __restrict__ w1_l0, const float* __restrict__ w2_l0, const float* __restrict__ w3_l0,
    const float* __restrict__ w1_l1, const float* __restrict__ w2_l1, const float* __restrict__ w3_l1,
    const float* __restrict__ tbl, const int* __restrict__ mono3,
    const int* __restrict__ mono2, float* __restrict__ out)
{
    const int b    = blockIdx.x;
    const int tid  = threadIdx.x;
    const int q    = __builtin_amdgcn_readfirstlane(tid >> 6);  // 0..3, SGPR
    const int lane = tid & 63;
    const int c0   = lane << 2;                 // 0,4,...,252

    __shared__ float xs[ELL][C_DIM];            //  9.2 KB
    __shared__ float P2[N_QUAD][C_DIM];         // 45.0 KB

    // ---- stage x (transposed) ----
    for (int t = tid; t < ELL * C_DIM; t += 256) {
        int i  = t >> 8;
        int cc = t & 255;
        xs[i][cc] = x[(size_t)(b*C_DIM + cc)*ELL + i];
    }
    __syncthreads();
    // ---- stage pair products ----
    for (int t = tid; t < N_QUAD * C_DIM; t += 256) {
        int p  = t >> 8;
        int cc = t & 255;
        int e2 = mono2[p];
        P2[p][cc] = xs[e2 & 15][cc] * xs[(e2 >> 4) & 15][cc];
    }
    __syncthreads();

    float acc3[4][K3];
    #pragma unroll
    for (int g = 0; g < 4; ++g)
        #pragma unroll
        for (int j = 0; j < K3; ++j) acc3[g][j] = 0.f;
    float acc2v[4][K2];
    #pragma unroll
    for (int g = 0; g < 4; ++g)
        #pragma unroll
        for (int j = 0; j < K2; ++j) acc2v[g][j] = 0.f;
    float acc1v[4] = {0.f, 0.f, 0.f, 0.f};

    const float* tq = tbl + q * Q_SIZE;         // wave-uniform -> s_load path

    // ---- cubic: 165 monomials ----
    #pragma unroll 2
    for (int m = 0; m < N_CUBIC; ++m) {
        int e3 = mono3[m];                      // uniform s_load
        int p  = e3 & 255;
        int c2 = e3 >> 8;
        float4 pp = *(const float4*)&P2[p][c0];
        float4 xx = *(const float4*)&xs[c2][c0];
        float x3_0 = pp.x * xx.x;
        float x3_1 = pp.y * xx.y;
        float x3_2 = pp.z * xx.z;
        float x3_3 = pp.w * xx.w;
        const float* r = tq + Q_CUBIC + m*K3;
        #pragma unroll
        for (int j = 0; j < K3; ++j) {
            float tv = r[j];                    // SGPR
            acc3[0][j] = fmaf(tv, x3_0, acc3[0][j]);
            acc3[1][j] = fmaf(tv, x3_1, acc3[1][j]);
            acc3[2][j] = fmaf(tv, x3_2, acc3[2][j]);
            acc3[3][j] = fmaf(tv, x3_3, acc3[3][j]);
        }
    }
    // ---- quadratic: 45 pairs (table rows in same pair order as P2) ----
    #pragma unroll 2
    for (int p = 0; p < N_QUAD; ++p) {
        float4 pp = *(const float4*)&P2[p][c0];
        const float* r = tq + Q_QUAD + p*K2;
        #pragma unroll
        for (int j = 0; j < K2; ++j) {
            float tv = r[j];
            acc2v[0][j] = fmaf(tv, pp.x, acc2v[0][j]);
            acc2v[1][j] = fmaf(tv, pp.y, acc2v[1][j]);
            acc2v[2][j] = fmaf(tv, pp.z, acc2v[2][j]);
            acc2v[3][j] = fmaf(tv, pp.w, acc2v[3][j]);
        }
    }
    // ---- linear ----
    #pragma unroll
    for (int i = 0; i < ELL; ++i) {
        float4 xx = *(const float4*)&xs[i][c0];
        float tv = tq[Q_LIN + i];
        acc1v[0] = fmaf(tv, xx.x, acc1v[0]);
        acc1v[1] = fmaf(tv, xx.y, acc1v[1]);
        acc1v[2] = fmaf(tv, xx.z, acc1v[2]);
        acc1v[3] = fmaf(tv, xx.w, acc1v[3]);
    }

    // ---- combine: w~[k,c] on the fly (weights are L2-hot, float4 loads) ----
    const float* w3 = (q == 0) ? w3_l0 : w3_l1;
    const float* w2 = (q == 0) ? w2_l0 : w2_l1;
    const float* w1 = (q == 0) ? w1_l0 : w1_l1;

    float yb[E_DIM];
    #pragma unroll
    for (int e = 0; e < E_DIM; ++e) yb[e] = y[b*E_DIM + e];  // b uniform -> s_load

    float o0 = 0.f, o1 = 0.f, o2 = 0.f, o3 = 0.f;
    #pragma unroll 4
    for (int k = 0; k < K3; ++k) {
        float wt0 = 0.f, wt1 = 0.f, wt2 = 0.f, wt3 = 0.f;
        #pragma unroll
        for (int e = 0; e < E_DIM; ++e) {
            float4 wv = *(const float4*)&w3[(e*K3 + k)*C_DIM + c0];
            wt0 = fmaf(yb[e], wv.x, wt0);
            wt1 = fmaf(yb[e], wv.y, wt1);
            wt2 = fmaf(yb[e], wv.z, wt2);
            wt3 = fmaf(yb[e], wv.w, wt3);
        }
        o0 = fmaf(wt0, acc3[0][k], o0);
        o1 = fmaf(wt1, acc3[1][k], o1);
        o2 = fmaf(wt2, acc3[2][k], o2);
        o3 = fmaf(wt3, acc3[3][k], o3);
    }
    #pragma unroll
    for (int k = 0; k < K2; ++k) {
        float wt0 = 0.f, wt1 = 0.f, wt2 = 0.f, wt3 = 0.f;
        #pragma unroll
        for (int e = 0; e < E_DIM; ++e) {
            float4 wv = *(const float4*)&w2[(e*K2 + k)*C_DIM + c0];
            wt0 = fmaf(yb[e], wv.x, wt0);
            wt1 = fmaf(yb[e], wv.y, wt1);
            wt2 = fmaf(yb[e], wv.z, wt2);
            wt3 = fmaf(yb[e], wv.w, wt3);
        }
        o0 = fmaf(wt0, acc2v[0][k], o0);
        o1 = fmaf(wt1, acc2v[1][k], o1);
        o2 = fmaf(wt2, acc2v[2][k], o2);
        o3 = fmaf(wt3, acc2v[3][k], o3);
    }
    {
        float wt0 = 0.f, wt1 = 0.f, wt2 = 0.f, wt3 = 0.f;
        #pragma unroll
        for (int e = 0; e < E_DIM; ++e) {
            float4 wv = *(const float4*)&w1[e*C_DIM + c0];
            wt0 = fmaf(yb[e], wv.x, wt0);
            wt1 = fmaf(yb[e], wv.y, wt1);
            wt2 = fmaf(yb[e], wv.z, wt2);
            wt3 = fmaf(yb[e], wv.w, wt3);
        }
        o0 = fmaf(wt0, acc1v[0], o0);
        o1 = fmaf(wt1, acc1v[1], o1);
        o2 = fmaf(wt2, acc1v[2], o2);
        o3 = fmaf(wt3, acc1v[3], o3);
    }

    if (q == 0) {
        *(float4*)&out[b*C_DIM + c0] = make_float4(o0, o1, o2, o3);
    } else {
        size_t base = (size_t)B_DIM*C_DIM + (size_t)(b*C_DIM + c0)*3 + (q - 1);
        out[base    ] = o0;
        out[base + 3] = o1;
        out[base + 6] = o2;
        out[base + 9] = o3;
    }
}

// ---------------------------------------------------------------------------
extern "C" void kernel_launch(void* const* d_in, const int* in_sizes, int n_in,
                              void* d_out, int out_size, void* d_ws, size_t ws_size,
                              hipStream_t stream)
{
    const float* x     = (const float*)d_in[0];
    const float* y     = (const float*)d_in[1];
    const float* U1_l0 = (const float*)d_in[2];
    const float* U2_l0 = (const float*)d_in[3];
    const float* U3_l0 = (const float*)d_in[4];
    const float* U1_l1 = (const float*)d_in[5];
    const float* U2_l1 = (const float*)d_in[6];
    const float* U3_l1 = (const float*)d_in[7];
    const float* w1_l0 = (const float*)d_in[8];
    const float* w2_l0 = (const float*)d_in[9];
    const float* w3_l0 = (const float*)d_in[10];
    const float* w1_l1 = (const float*)d_in[11];
    const float* w2_l1 = (const float*)d_in[12];
    const float* w3_l1 = (const float*)d_in[13];

    float* tbl = (float*)d_ws;               // 56.7 KB used
    const int* mono3 = (const int*)((float*)d_ws + MONO3_OFF);
    const int* mono2 = (const int*)((float*)d_ws + MONO2_OFF);
    float* outp = (float*)d_out;

    build_tables<<<(WS_TOTAL + 255)/256, 256, 0, stream>>>(
        U1_l0, U2_l0, U3_l0, U1_l1, U2_l1, U3_l1, tbl);

    symcon_main<<<B_DIM, 256, 0, stream>>>(
        x, y, w1_l0, w2_l0, w3_l0, w1_l1, w2_l1, w3_l1, tbl, mono3, mono2, outp);
}